// Round 4
// baseline (571.041 us; speedup 1.0000x reference)
//
#include <hip/hip_runtime.h>
#include <type_traits>

#define FDIM 128
#define NSLICE 8          // 8 feature slices of 16 bf16 (= 8 dwords) each

typedef __attribute__((ext_vector_type(8))) short short8v;   // 8 bf16
typedef __attribute__((ext_vector_type(4))) float f32x4;

// ---------- bf16 helpers (manual, RNE) ----------
__device__ __forceinline__ uint16_t f2bf(float f) {
    uint32_t u = __float_as_uint(f);
    uint32_t r = (u + 0x7fffu + ((u >> 16) & 1u)) >> 16;
    return (uint16_t)r;
}
__device__ __forceinline__ uint32_t pack_bf16(float a, float b) {
    return (uint32_t)f2bf(a) | ((uint32_t)f2bf(b) << 16);
}
__device__ __forceinline__ float bflo(uint32_t u) { return __uint_as_float(u << 16); }
__device__ __forceinline__ float bfhi(uint32_t u) { return __uint_as_float(u & 0xffff0000u); }

// Sliced bf16 matrix layout: dword index of (slice s, row r, dword f in [0,8))
//   = s*(N*8) + r*8 + f          (slice = features [16s, 16s+16))

// ---------------------------------------------------------------------------
// Kernel 1: row_ptr[i] = lower_bound(rows, i). rows sorted.
// ---------------------------------------------------------------------------
__global__ __launch_bounds__(256) void build_row_ptr_k(const int* __restrict__ rows,
                                                       int E, int N,
                                                       int* __restrict__ rp) {
    int i = blockIdx.x * 256 + threadIdx.x;
    if (i > N) return;
    int lo = 0, hi = E;
    while (lo < hi) {
        int mid = (lo + hi) >> 1;
        if (rows[mid] < i) lo = mid + 1; else hi = mid;
    }
    rp[i] = lo;
}

// ---------------------------------------------------------------------------
// Kernel 1b: Wt[n][k] = bf16(W[k][n]), 128x128.
// ---------------------------------------------------------------------------
__global__ __launch_bounds__(256) void transpose_w_k(const float* __restrict__ W,
                                                     uint16_t* __restrict__ Wt) {
    int idx = blockIdx.x * 256 + threadIdx.x;   // 0..16383
    int k = idx >> 7, n = idx & 127;
    Wt[n * FDIM + k] = f2bf(W[k * FDIM + n]);
}

// ---------------------------------------------------------------------------
// Kernel 2: C = A @ W via bf16 MFMA 16x16x32.
// A: f32 row-major (ABF=0) or bf16 SLICED (ABF=1). C: bf16 SLICED.
// Block = 256 thr (4 waves), tile M=128, N=128, K=128.
// ---------------------------------------------------------------------------
template <int ABF>
__global__ __launch_bounds__(256) void gemm_mfma_k(const void* __restrict__ A_,
                                                   const uint16_t* __restrict__ Wt,
                                                   uint32_t* __restrict__ C, int M) {
    const int t = threadIdx.x;
    const int w = t >> 6;               // wave 0..3
    const int l = t & 63;
    const int row0 = blockIdx.x * 128 + w * 32;

    f32x4 acc[2][8];
#pragma unroll
    for (int mf = 0; mf < 2; ++mf)
#pragma unroll
        for (int nf = 0; nf < 8; ++nf) acc[mf][nf] = (f32x4)0.f;

    const int lr = l & 15;
    const int kg = l >> 4;

#pragma unroll
    for (int ks = 0; ks < 4; ++ks) {
        const int k0 = ks * 32 + kg * 8;
        short8v a[2];
#pragma unroll
        for (int mf = 0; mf < 2; ++mf) {
            int r = row0 + mf * 16 + lr;
            if (r >= M) r = M - 1;      // safe clamp; stores guarded
            if constexpr (ABF) {
                // sliced bf16: slice = k0>>4, in-slice offset = k0&15 (0 or 8)
                const uint16_t* ap = (const uint16_t*)A_ +
                    (size_t)(k0 >> 4) * ((size_t)M * 16) + (size_t)r * 16 + (k0 & 15);
                a[mf] = *(const short8v*)ap;
            } else {
                const float* ap = (const float*)A_ + (size_t)r * FDIM + k0;
                float4 f0 = *(const float4*)(ap);
                float4 f1 = *(const float4*)(ap + 4);
                uint32_t p0 = pack_bf16(f0.x, f0.y), p1 = pack_bf16(f0.z, f0.w);
                uint32_t p2 = pack_bf16(f1.x, f1.y), p3 = pack_bf16(f1.z, f1.w);
                uint4 u = make_uint4(p0, p1, p2, p3);
                a[mf] = *(short8v*)&u;
            }
        }
#pragma unroll
        for (int nf = 0; nf < 8; ++nf) {
            short8v b = *(const short8v*)(Wt + (size_t)(nf * 16 + lr) * FDIM + k0);
            acc[0][nf] = __builtin_amdgcn_mfma_f32_16x16x32_bf16(a[0], b, acc[0][nf], 0, 0, 0);
            acc[1][nf] = __builtin_amdgcn_mfma_f32_16x16x32_bf16(a[1], b, acc[1][nf], 0, 0, 0);
        }
    }

    // store sliced: col = nf*16+lr -> slice = nf, dword-in-slice = lr>>1
    const int colpar = l & 1;
#pragma unroll
    for (int mf = 0; mf < 2; ++mf) {
#pragma unroll
        for (int nf = 0; nf < 8; ++nf) {
#pragma unroll
            for (int j = 0; j < 4; ++j) {
                float v = acc[mf][nf][j];
                float pv = __shfl_xor(v, 1);
                int row = row0 + mf * 16 + kg * 4 + j;
                if (!colpar && row < M) {
                    C[(size_t)nf * ((size_t)M * 8) + (size_t)row * 8 + (lr >> 1)] =
                        pack_bf16(v, pv);
                }
            }
        }
    }
}

// ---------------------------------------------------------------------------
// Kernel 3: sliced SPMM. slice = blockIdx % 8 (XCD-pinned: 3.2MB slice fits
// the 4MB per-XCD L2). Wave lanes = (ep in [0,8), f in [0,8)): 8 edges x
// 8 dwords per iteration group of 32 edges; cols/vals loaded wave-wide once
// per 32 edges, extracted via shfl. f32 accumulate, reduce across ep.
// OUT_SLICED=1 -> bf16 sliced; else f32 row-major [N][128].
// ---------------------------------------------------------------------------
template <int RELU, int OUT_SLICED>
__global__ __launch_bounds__(256) void spmm_sliced_k(const int* __restrict__ rp,
                                                     const int* __restrict__ cols,
                                                     const float* __restrict__ vals,
                                                     const uint32_t* __restrict__ Xs,
                                                     const float* __restrict__ bias,
                                                     void* __restrict__ out, int N) {
    const int s    = blockIdx.x & 7;
    const int g0   = blockIdx.x >> 3;
    const int gs   = gridDim.x >> 3;
    const int wave = threadIdx.x >> 6;
    const int lane = threadIdx.x & 63;
    const int f    = lane & 7;
    const int ep   = lane >> 3;
    const int l31  = lane & 31;

    const uint32_t* X_s = Xs + (size_t)s * ((size_t)N * 8);
    const float2 bb = *(const float2*)(bias + s * 16 + 2 * f);

    for (int r = g0 * 4 + wave; r < N; r += gs * 4) {
        int s_ = __builtin_amdgcn_readfirstlane(rp[r]);
        int e_ = __builtin_amdgcn_readfirstlane(rp[r + 1]);

        float alo = 0.f, ahi = 0.f;
        for (int i = s_; i < e_; i += 32) {
            int   li = i + l31;
            int   cl = li < e_ ? li : e_ - 1;
            int   creg = cols[cl];
            float vreg = (li < e_) ? vals[cl] : 0.f;
#pragma unroll
            for (int t = 0; t < 4; ++t) {
                if (i + t * 8 < e_) {                 // wave-uniform guard
                    int   j = t * 8 + ep;
                    int   c = __shfl(creg, j);
                    float v = __shfl(vreg, j);
                    uint32_t u = X_s[(size_t)c * 8 + f];
                    alo = fmaf(v, bflo(u), alo);
                    ahi = fmaf(v, bfhi(u), ahi);
                }
            }
        }
        // reduce across ep groups (xor 8,16,32)
#pragma unroll
        for (int m = 8; m < 64; m <<= 1) {
            alo += __shfl_xor(alo, m);
            ahi += __shfl_xor(ahi, m);
        }
        alo += bb.x; ahi += bb.y;
        if (RELU) { alo = fmaxf(alo, 0.f); ahi = fmaxf(ahi, 0.f); }

        if (ep == 0) {
            if constexpr (OUT_SLICED) {
                ((uint32_t*)out)[(size_t)s * ((size_t)N * 8) + (size_t)r * 8 + f] =
                    pack_bf16(alo, ahi);
            } else {
                *(float2*)((float*)out + (size_t)r * FDIM + s * 16 + 2 * f) =
                    make_float2(alo, ahi);
            }
        }
    }
}

// ---------------------------------------------------------------------------
extern "C" void kernel_launch(void* const* d_in, const int* in_sizes, int n_in,
                              void* d_out, int out_size, void* d_ws, size_t ws_size,
                              hipStream_t stream) {
    const float* features = (const float*)d_in[0];
    const int*   adj_rows = (const int*)d_in[1];
    const int*   adj_cols = (const int*)d_in[2];
    const float* adj_vals = (const float*)d_in[3];
    const float* W1       = (const float*)d_in[4];
    const float* b1       = (const float*)d_in[5];
    const float* W2       = (const float*)d_in[6];
    const float* b2       = (const float*)d_in[7];

    const int N = in_sizes[0] / FDIM;    // 100000
    const int E = in_sizes[1];           // 3200000
    float* out = (float*)d_out;

    char* ws = (char*)d_ws;
    int* rp = (int*)ws;
    size_t rp_bytes = (((size_t)(N + 1) * sizeof(int)) + 255) & ~(size_t)255;
    uint32_t* XWb = (uint32_t*)(ws + rp_bytes);          // sliced bf16, N*128 (25.6 MB)
    uint32_t* Hb  = XWb + (size_t)N * 64;                // sliced bf16, N*128 (25.6 MB)
    uint16_t* W1t = (uint16_t*)(Hb + (size_t)N * 64);    // 128*128 bf16 (32 KB)
    uint16_t* W2t = W1t + FDIM * FDIM;                   // 128*128 bf16 (32 KB)

    const int nblk_gemm = (N + 127) / 128;
    const int nblk_spmm = 8 * 2048;      // slice = blockIdx % 8 (XCD-pinned)

    // 1. CSR row_ptr + W transposes
    build_row_ptr_k<<<(N + 256) / 256, 256, 0, stream>>>(adj_rows, E, N, rp);
    transpose_w_k<<<64, 256, 0, stream>>>(W1, W1t);
    transpose_w_k<<<64, 256, 0, stream>>>(W2, W2t);
    // 2. XWb = bf16(X @ W1)        (MFMA, writes sliced)
    gemm_mfma_k<0><<<nblk_gemm, 256, 0, stream>>>((const void*)features, W1t, XWb, N);
    // 3. Hb = bf16(relu(A @ XWb + b1))   (sliced SPMM, sliced out)
    spmm_sliced_k<1, 1><<<nblk_spmm, 256, 0, stream>>>(rp, adj_cols, adj_vals,
                                                       XWb, b1, (void*)Hb, N);
    // 4. XWb = bf16(Hb @ W2)       (MFMA, reads+writes sliced)
    gemm_mfma_k<1><<<nblk_gemm, 256, 0, stream>>>((const void*)Hb, W2t, XWb, N);
    // 5. out = A @ XWb + b2        (sliced SPMM, f32 row-major out)
    spmm_sliced_k<0, 0><<<nblk_spmm, 256, 0, stream>>>(rp, adj_cols, adj_vals,
                                                       XWb, b2, (void*)out, N);
}